// Round 5
// baseline (797.940 us; speedup 1.0000x reference)
//
#include <hip/hip_runtime.h>
#include <math.h>

#define BB 2
#define TT 2048
#define DD 1024
#define NTHREADS 256

#define RT 64               // rows per score tile
#define CT 128              // cols per score tile (= top-K window width)
#define DC 64               // d-halves per chunk (2 MFMA K-steps)
#define NCHUNK (DD / DC)    // 16
#define NJC (TT / CT)       // 16 windows per row
#define KMAX 16
#define CST 132             // score-tile stride: 4 mod 32 -> 2-way (free) scans
#define NTILES 272          // causal 64x128 tiles per batch

typedef _Float16 half8  __attribute__((ext_vector_type(8)));
typedef _Float16 half4v __attribute__((ext_vector_type(4)));
typedef float    float4v __attribute__((ext_vector_type(4)));

__device__ __forceinline__ float gelu_exact(float t) {
    return 0.5f * t * (1.0f + erff(t * 0.70710678118654752f));
}

// ---- Kernel P: split fp32 h into fp16 hi/lo planes ----------------------
__global__ __launch_bounds__(NTHREADS) void split_kernel(
    const float* __restrict__ h,
    _Float16* __restrict__ hiP,
    _Float16* __restrict__ loP)
{
    const int idx = blockIdx.x * NTHREADS + threadIdx.x;
    const float4 v = ((const float4*)h)[idx];
    const float xs[4] = {v.x, v.y, v.z, v.w};
    half4v hi, lo;
    #pragma unroll
    for (int u = 0; u < 4; ++u) {
        const _Float16 hh = (_Float16)xs[u];
        hi[u] = hh;
        lo[u] = (_Float16)(xs[u] - (float)hh);
    }
    ((half4v*)hiP)[idx] = hi;
    ((half4v*)loP)[idx] = lo;
}

// ---- Kernel S: causal 64x128 score tile via split-fp16 MFMA + window top-K ----
// LDS staging regions (granule = 16 B = 8 halves), fragment-lane order:
//   A-hi granules [0,512): n = s*256 + band*64 + q*16 + r   (band<4, s<2)
//   A-lo [512,1024) ; B-hi [1024,2048): n = s*512 + band*64 + q*16 + r (band<8)
//   B-lo [2048,3072).  Frag read for (s,band): granule = regbase + (s*B+band)*64 + lane.
__global__ __launch_bounds__(NTHREADS) void score_topk_kernel(
    const _Float16* __restrict__ hiP,
    const _Float16* __restrict__ loP,
    float* __restrict__ pval,   // (B,T,NJC,KMAX)
    int*   __restrict__ pidx,   // (B,T,NJC,KMAX)
    int K)
{
    __shared__ __align__(16) char smem_raw[49152];  // 48 KB union: staging / 64x132 f32 scores
    __shared__ float s_pv[RT][4];
    __shared__ int   s_pc[RT][4];
    _Float16* sm    = (_Float16*)smem_raw;
    float* scores   = (float*)smem_raw;

    // triangular decode: p -> (it, jc); it in [0,32), jc in [0, it/2]
    const int b = blockIdx.y;
    const int p = blockIdx.x;
    int g = (int)(0.5f * (sqrtf(4.0f * (float)p + 1.0f) - 1.0f));
    while ((g + 1) * (g + 2) <= p) ++g;
    while (g * (g + 1) > p) --g;
    const int qq = p - g * (g + 1);
    const int it = 2 * g + qq / (g + 1);
    const int jc = qq % (g + 1);
    const int i0 = it * RT, j0 = jc * CT;

    const int tid  = threadIdx.x;
    const int lane = tid & 63, wave = tid >> 6;
    const int wr = wave & 1, wc = wave >> 1;
    const size_t pbase = (size_t)b * TT * DD;

    // staging slots: 12 granules per thread, LDS granule index = gr = tid + 256*slot
    const _Float16* gptr[12];
    #pragma unroll
    for (int slot = 0; slot < 12; ++slot) {
        const int gr = tid + NTHREADS * slot;   // 0..3071
        int n, row;
        const _Float16* plane;
        int sA;
        if (gr < 512)       { n = gr;        plane = hiP; row = i0 + ((n >> 6) & 3) * 16 + (n & 15); sA = n >> 8; }
        else if (gr < 1024) { n = gr - 512;  plane = loP; row = i0 + ((n >> 6) & 3) * 16 + (n & 15); sA = n >> 8; }
        else if (gr < 2048) { n = gr - 1024; plane = hiP; row = j0 + ((n >> 6) & 7) * 16 + (n & 15); sA = n >> 9; }
        else                { n = gr - 2048; plane = loP; row = j0 + ((n >> 6) & 7) * 16 + (n & 15); sA = n >> 9; }
        const int q   = (n >> 4) & 3;
        const int oct = sA * 4 + q;             // d-octet within chunk (0..7)
        gptr[slot] = plane + pbase + (size_t)row * DD + oct * 8;
    }

    float4v acc[2][4];
    #pragma unroll
    for (int rb = 0; rb < 2; ++rb)
        #pragma unroll
        for (int cb = 0; cb < 4; ++cb)
            acc[rb][cb] = (float4v){0.f, 0.f, 0.f, 0.f};

    // prefetch chunk 0
    uint4 stg[12];
    #pragma unroll
    for (int t = 0; t < 12; ++t) stg[t] = *(const uint4*)gptr[t];

    for (int c = 0; c < NCHUNK; ++c) {
        __syncthreads();
        #pragma unroll
        for (int t = 0; t < 12; ++t)
            *(uint4*)&sm[(size_t)(tid + NTHREADS * t) * 8] = stg[t];
        __syncthreads();
        if (c + 1 < NCHUNK) {
            #pragma unroll
            for (int t = 0; t < 12; ++t) stg[t] = *(const uint4*)(gptr[t] + (c + 1) * DC);
        }
        #pragma unroll
        for (int s = 0; s < 2; ++s) {
            half8 ah[2], al[2], bh[4], bl[4];
            #pragma unroll
            for (int rb = 0; rb < 2; ++rb) {
                const int band = 2 * wr + rb;
                ah[rb] = *(const half8*)&sm[        ((s * 4 + band) * 64 + lane) * 8];
                al[rb] = *(const half8*)&sm[4096 +  ((s * 4 + band) * 64 + lane) * 8];
            }
            #pragma unroll
            for (int cb = 0; cb < 4; ++cb) {
                const int band = 4 * wc + cb;
                bh[cb] = *(const half8*)&sm[8192  + ((s * 8 + band) * 64 + lane) * 8];
                bl[cb] = *(const half8*)&sm[16384 + ((s * 8 + band) * 64 + lane) * 8];
            }
            #pragma unroll
            for (int rb = 0; rb < 2; ++rb)
                #pragma unroll
                for (int cb = 0; cb < 4; ++cb) {
                    acc[rb][cb] = __builtin_amdgcn_mfma_f32_16x16x32_f16(ah[rb], bh[cb], acc[rb][cb], 0, 0, 0);
                    acc[rb][cb] = __builtin_amdgcn_mfma_f32_16x16x32_f16(ah[rb], bl[cb], acc[rb][cb], 0, 0, 0);
                    acc[rb][cb] = __builtin_amdgcn_mfma_f32_16x16x32_f16(al[rb], bh[cb], acc[rb][cb], 0, 0, 0);
                }
        }
    }
    __syncthreads();   // all frag reads done before overwriting staging with scores

    // masked score tile into LDS. C/D: col = lane&15, row = (lane>>4)*4 + reg
    {
        const int qn = lane >> 4, rn = lane & 15;
        #pragma unroll
        for (int rb = 0; rb < 2; ++rb)
            #pragma unroll
            for (int cb = 0; cb < 4; ++cb)
                #pragma unroll
                for (int reg = 0; reg < 4; ++reg) {
                    const int i_loc = 32 * wr + 16 * rb + qn * 4 + reg;
                    const int j_loc = 64 * wc + 16 * cb + rn;
                    scores[i_loc * CST + j_loc] =
                        (j0 + j_loc <= i0 + i_loc) ? acc[rb][cb][reg] : -INFINITY;
                }
    }
    __syncthreads();

    // per-window top-K: 4 threads/row, K argmax passes
    const int rloc = tid >> 2, seg = tid & 3;
    float* Crow = scores + rloc * CST;
    const int irow = i0 + rloc;
    for (int k = 0; k < K; ++k) {
        float best = -INFINITY; int bc = -1;
        #pragma unroll
        for (int cc = 0; cc < 32; ++cc) {
            const int c = seg + (cc << 2);
            const float v = Crow[c];
            if (v > best) { best = v; bc = c; }
        }
        s_pv[rloc][seg] = best; s_pc[rloc][seg] = bc;
        __syncthreads();
        if (seg == 0) {
            float bv = best; int bcc = bc;
            #pragma unroll
            for (int s2 = 1; s2 < 4; ++s2) {
                const float v = s_pv[rloc][s2]; const int c2 = s_pc[rloc][s2];
                if (c2 >= 0 && (v > bv || (v == bv && (bcc < 0 || c2 < bcc)))) { bv = v; bcc = c2; }
            }
            const size_t base = ((size_t)(b * TT + irow) * NJC + jc) * KMAX + k;
            pval[base] = bv;
            pidx[base] = (bcc >= 0) ? (j0 + bcc) : -1;
            if (bcc >= 0) Crow[bcc] = -INFINITY;
        }
        __syncthreads();
    }
}

// ---- Kernel T: merge window top-Ks, gather, epilogue (optional fused final) ----
__global__ __launch_bounds__(NTHREADS) void merge_agg_kernel(
    const float* __restrict__ h_in,
    float* __restrict__ h_out,
    const float* __restrict__ pval,
    const int*   __restrict__ pidx,
    const float* __restrict__ gain,
    const float* __restrict__ bias,
    const float* __restrict__ log_mix_r,
    const float* __restrict__ log_momentum,
    int K,
    const float* __restrict__ xres,       // non-null => fused (h-x)*scale
    const float* __restrict__ log_scale)
{
    __shared__ float s_wv[4];
    __shared__ int   s_wj[4];
    __shared__ int   s_sel[KMAX];

    const int row = blockIdx.x, b = row / TT, i = row % TT;
    const int tid = threadIdx.x, lane = tid & 63, wave = tid >> 6;
    const float* hb = h_in + (size_t)b * TT * DD;

    const int jcn = i / CT + 1;
    const int ncand = jcn * K;          // <= 256
    float mv = -INFINITY; int mj = -1;
    if (tid < ncand) {
        const int w = tid / K, k = tid - w * K;
        const size_t base = ((size_t)(b * TT + i) * NJC + w) * KMAX + k;
        const int j = pidx[base];
        if (j >= 0) { mj = j; mv = pval[base]; }
    }

    const int count = (i + 1 < K) ? (i + 1) : K;
    for (int k = 0; k < count; ++k) {
        float v = mv; int j = mj;
        #pragma unroll
        for (int off = 32; off >= 1; off >>= 1) {
            const float ov = __shfl_down(v, off, 64);
            const int   oj = __shfl_down(j, off, 64);
            if (oj >= 0 && (ov > v || (ov == v && (j < 0 || oj < j)))) { v = ov; j = oj; }
        }
        if (lane == 0) { s_wv[wave] = v; s_wj[wave] = j; }
        __syncthreads();
        if (tid == 0) {
            float bv = s_wv[0]; int bj = s_wj[0];
            #pragma unroll
            for (int w = 1; w < 4; ++w) {
                const float wv = s_wv[w]; const int wj = s_wj[w];
                if (wj >= 0 && (wv > bv || (wv == bv && (bj < 0 || wj < bj)))) { bv = wv; bj = wj; }
            }
            s_sel[k] = bj;
        }
        __syncthreads();
        if (mj >= 0 && mj == s_sel[k]) { mv = -INFINITY; mj = -1; }
    }

    const float mix      = 1.0f / (1.0f + expf(-log_mix_r[0]));
    const float momentum = 1.0f / (1.0f + expf(-log_momentum[0]));
    const float inv_cnt  = 1.0f / (float)count;

    float4 msg = make_float4(0.f, 0.f, 0.f, 0.f);
    for (int k = 0; k < count; ++k) {
        const float4 v = ((const float4*)(hb + (size_t)s_sel[k] * DD))[tid];
        msg.x += v.x; msg.y += v.y; msg.z += v.z; msg.w += v.w;
    }

    const float4 hi = ((const float4*)(hb + (size_t)i * DD))[tid];
    const float4 g4 = ((const float4*)gain)[tid];
    const float4 c4 = ((const float4*)bias)[tid];

    float4 o;
    {
        float m, t;
        m = msg.x * inv_cnt; t = (mix * hi.x + (1.f - mix) * m) * g4.x + c4.x;
        o.x = momentum * hi.x + (1.f - momentum) * gelu_exact(t);
        m = msg.y * inv_cnt; t = (mix * hi.y + (1.f - mix) * m) * g4.y + c4.y;
        o.y = momentum * hi.y + (1.f - momentum) * gelu_exact(t);
        m = msg.z * inv_cnt; t = (mix * hi.z + (1.f - mix) * m) * g4.z + c4.z;
        o.z = momentum * hi.z + (1.f - momentum) * gelu_exact(t);
        m = msg.w * inv_cnt; t = (mix * hi.w + (1.f - mix) * m) * g4.w + c4.w;
        o.w = momentum * hi.w + (1.f - momentum) * gelu_exact(t);
    }

    if (xres != nullptr) {
        const float scale = log1pf(expf(log_scale[0])) + 0.01f;
        const float4 xv = ((const float4*)(xres + (size_t)row * DD))[tid];
        o.x = (o.x - xv.x) * scale;
        o.y = (o.y - xv.y) * scale;
        o.z = (o.z - xv.z) * scale;
        o.w = (o.w - xv.w) * scale;
    }
    ((float4*)(h_out + (size_t)row * DD))[tid] = o;
}

extern "C" void kernel_launch(void* const* d_in, const int* in_sizes, int n_in,
                              void* d_out, int out_size, void* d_ws, size_t ws_size,
                              hipStream_t stream) {
    const float* x            = (const float*)d_in[0];
    const float* gain         = (const float*)d_in[1];
    const float* bias         = (const float*)d_in[2];
    const float* log_mix      = (const float*)d_in[3];
    const float* log_momentum = (const float*)d_in[4];
    const float* log_scale    = (const float*)d_in[5];
    float* out = (float*)d_out;

    // ws: h (16.78 MB) | pval (8.39) | pidx (8.39) | hiP (8.39) | loP (8.39)
    char* wsb = (char*)d_ws;
    float*     h_ws = (float*)wsb;
    float*     pval = (float*)(wsb + (size_t)BB * TT * DD * 4);
    int*       pidx = (int*)  (wsb + (size_t)BB * TT * DD * 4 + (size_t)BB * TT * NJC * KMAX * 4);
    _Float16*  hiP  = (_Float16*)(wsb + (size_t)BB * TT * DD * 4 + (size_t)BB * TT * NJC * KMAX * 8);
    _Float16*  loP  = hiP + (size_t)BB * TT * DD;

    const dim3 sgrid(NTILES, BB);
    const int nsplit = BB * TT * DD / 4 / NTHREADS;   // 4096

    // round 0: x -> out
    split_kernel<<<nsplit, NTHREADS, 0, stream>>>(x, hiP, loP);
    score_topk_kernel<<<sgrid, NTHREADS, 0, stream>>>(hiP, loP, pval, pidx, 4);
    merge_agg_kernel<<<BB * TT, NTHREADS, 0, stream>>>(
        x, out, pval, pidx, gain + 0 * DD, bias + 0 * DD, log_mix + 0, log_momentum, 4,
        nullptr, nullptr);
    // round 1: out -> h_ws
    split_kernel<<<nsplit, NTHREADS, 0, stream>>>(out, hiP, loP);
    score_topk_kernel<<<sgrid, NTHREADS, 0, stream>>>(hiP, loP, pval, pidx, 8);
    merge_agg_kernel<<<BB * TT, NTHREADS, 0, stream>>>(
        out, h_ws, pval, pidx, gain + 1 * DD, bias + 1 * DD, log_mix + 1, log_momentum, 8,
        nullptr, nullptr);
    // round 2 (fused finalize): h_ws -> out
    split_kernel<<<nsplit, NTHREADS, 0, stream>>>(h_ws, hiP, loP);
    score_topk_kernel<<<sgrid, NTHREADS, 0, stream>>>(hiP, loP, pval, pidx, 16);
    merge_agg_kernel<<<BB * TT, NTHREADS, 0, stream>>>(
        h_ws, out, pval, pidx, gain + 2 * DD, bias + 2 * DD, log_mix + 2, log_momentum, 16,
        x, log_scale);
}

// Round 6
// 439.004 us; speedup vs baseline: 1.8176x; 1.8176x over previous
//
#include <hip/hip_runtime.h>
#include <math.h>

#define BB 2
#define TT 2048
#define DD 1024
#define NTHREADS 256

#define RT 64               // rows per score tile
#define CT 128              // cols per score tile (= top-K window width)
#define DC 64               // d-halves per chunk (2 MFMA K-steps)
#define NCHUNK (DD / DC)    // 16
#define NJC (TT / CT)       // 16 windows per row
#define KMAX 16
#define CST 132             // score-tile stride: 4 mod 32 -> 2-way (free) scans
#define NTILES 272          // causal 64x128 tiles per batch
#define PLANE ((uint32_t)(BB * TT * DD))   // halves per plane (hi->lo offset)

typedef _Float16 half8  __attribute__((ext_vector_type(8)));
typedef _Float16 half4v __attribute__((ext_vector_type(4)));
typedef float    float4v __attribute__((ext_vector_type(4)));

#define GLD16(gp, lp) __builtin_amdgcn_global_load_lds(                         \
    (const __attribute__((address_space(1))) unsigned int*)(gp),                \
    (__attribute__((address_space(3))) unsigned int*)(lp), 16, 0, 0)

__device__ __forceinline__ float gelu_exact(float t) {
    return 0.5f * t * (1.0f + erff(t * 0.70710678118654752f));
}

// ---- Kernel P: split fp32 h into fp16 hi/lo planes (round 0 only) -------
__global__ __launch_bounds__(NTHREADS) void split_kernel(
    const float* __restrict__ h,
    _Float16* __restrict__ hiP,
    _Float16* __restrict__ loP)
{
    const int idx = blockIdx.x * NTHREADS + threadIdx.x;
    const float4 v = ((const float4*)h)[idx];
    const float xs[4] = {v.x, v.y, v.z, v.w};
    half4v hi, lo;
    #pragma unroll
    for (int u = 0; u < 4; ++u) {
        const _Float16 hh = (_Float16)xs[u];
        hi[u] = hh;
        lo[u] = (_Float16)(xs[u] - (float)hh);
    }
    ((half4v*)hiP)[idx] = hi;
    ((half4v*)loP)[idx] = lo;
}

// ---- Kernel S: causal 64x128 score tile via split-fp16 MFMA + window top-K ----
// Staging (async global->LDS, granule = 16 B, fragment-lane order):
//   A-hi granules [0,512), A-lo [512,1024), B-hi [1024,2048), B-lo [2048,3072).
//   Deposit for slot t: LDS byte (tid + 256 t)*16 = wave-uniform + lane*16.
__global__ __launch_bounds__(NTHREADS) void score_topk_kernel(
    const _Float16* __restrict__ hiP,   // loP = hiP + PLANE
    float* __restrict__ pval,   // (B,T,NJC,KMAX)
    int*   __restrict__ pidx,   // (B,T,NJC,KMAX)
    int K)
{
    __shared__ __align__(16) char smem_raw[49152];  // 48 KB union: staging / 64x132 f32 scores
    __shared__ float s_pv[RT][4];
    __shared__ int   s_pc[RT][4];
    _Float16* sm  = (_Float16*)smem_raw;
    float* scores = (float*)smem_raw;

    // triangular decode: p -> (it, jc); it in [0,32), jc in [0, it/2]
    const int b = blockIdx.y;
    const int p = blockIdx.x;
    int g = (int)(0.5f * (sqrtf(4.0f * (float)p + 1.0f) - 1.0f));
    while ((g + 1) * (g + 2) <= p) ++g;
    while (g * (g + 1) > p) --g;
    const int qq = p - g * (g + 1);
    const int it = 2 * g + qq / (g + 1);
    const int jc = qq % (g + 1);
    const int i0 = it * RT, j0 = jc * CT;

    const int tid  = threadIdx.x;
    const int lane = tid & 63, wave = tid >> 6;
    const int wr = wave & 1, wc = wave >> 1;

    // per-slot global offsets (halves, off hiP); 12 u32 regs, one SGPR base
    uint32_t goff[12];
    #pragma unroll
    for (int slot = 0; slot < 12; ++slot) {
        const int gr = tid + NTHREADS * slot;   // 0..3071
        int n, row; uint32_t pl; int sA;
        if (gr < 512)       { n = gr;        pl = 0; row = i0 + ((n >> 6) & 3) * 16 + (n & 15); sA = n >> 8; }
        else if (gr < 1024) { n = gr - 512;  pl = 1; row = i0 + ((n >> 6) & 3) * 16 + (n & 15); sA = n >> 8; }
        else if (gr < 2048) { n = gr - 1024; pl = 0; row = j0 + ((n >> 6) & 7) * 16 + (n & 15); sA = n >> 9; }
        else                { n = gr - 2048; pl = 1; row = j0 + ((n >> 6) & 7) * 16 + (n & 15); sA = n >> 9; }
        const int q   = (n >> 4) & 3;
        const int oct = sA * 4 + q;             // d-octet within chunk (0..7)
        goff[slot] = pl * PLANE + (uint32_t)(b * TT + row) * DD + (uint32_t)oct * 8;
    }

    float4v acc[2][4];
    #pragma unroll
    for (int rb = 0; rb < 2; ++rb)
        #pragma unroll
        for (int cb = 0; cb < 4; ++cb)
            acc[rb][cb] = (float4v){0.f, 0.f, 0.f, 0.f};

    for (int c = 0; c < NCHUNK; ++c) {
        __syncthreads();    // prior chunk's frag reads done before overwrite
        #pragma unroll
        for (int t = 0; t < 12; ++t)
            GLD16(hiP + goff[t] + c * DC, &sm[(size_t)(tid + NTHREADS * t) * 8]);
        __syncthreads();    // vmcnt(0) drain: staging visible

        #pragma unroll
        for (int s = 0; s < 2; ++s) {
            half8 ah[2], al[2], bh[4], bl[4];
            #pragma unroll
            for (int rb = 0; rb < 2; ++rb) {
                const int band = 2 * wr + rb;
                ah[rb] = *(const half8*)&sm[        ((s * 4 + band) * 64 + lane) * 8];
                al[rb] = *(const half8*)&sm[4096 +  ((s * 4 + band) * 64 + lane) * 8];
            }
            #pragma unroll
            for (int cb = 0; cb < 4; ++cb) {
                const int band = 4 * wc + cb;
                bh[cb] = *(const half8*)&sm[8192  + ((s * 8 + band) * 64 + lane) * 8];
                bl[cb] = *(const half8*)&sm[16384 + ((s * 8 + band) * 64 + lane) * 8];
            }
            #pragma unroll
            for (int rb = 0; rb < 2; ++rb)
                #pragma unroll
                for (int cb = 0; cb < 4; ++cb) {
                    acc[rb][cb] = __builtin_amdgcn_mfma_f32_16x16x32_f16(ah[rb], bh[cb], acc[rb][cb], 0, 0, 0);
                    acc[rb][cb] = __builtin_amdgcn_mfma_f32_16x16x32_f16(ah[rb], bl[cb], acc[rb][cb], 0, 0, 0);
                    acc[rb][cb] = __builtin_amdgcn_mfma_f32_16x16x32_f16(al[rb], bh[cb], acc[rb][cb], 0, 0, 0);
                }
        }
    }
    __syncthreads();   // all frag reads done before overwriting staging with scores

    // masked score tile into LDS. C/D: col = lane&15, row = (lane>>4)*4 + reg
    {
        const int qn = lane >> 4, rn = lane & 15;
        #pragma unroll
        for (int rb = 0; rb < 2; ++rb)
            #pragma unroll
            for (int cb = 0; cb < 4; ++cb)
                #pragma unroll
                for (int reg = 0; reg < 4; ++reg) {
                    const int i_loc = 32 * wr + 16 * rb + qn * 4 + reg;
                    const int j_loc = 64 * wc + 16 * cb + rn;
                    scores[i_loc * CST + j_loc] =
                        (j0 + j_loc <= i0 + i_loc) ? acc[rb][cb][reg] : -INFINITY;
                }
    }
    __syncthreads();

    // per-window top-K: 4 threads/row, K argmax passes
    const int rloc = tid >> 2, seg = tid & 3;
    float* Crow = scores + rloc * CST;
    const int irow = i0 + rloc;
    for (int k = 0; k < K; ++k) {
        float best = -INFINITY; int bc = -1;
        #pragma unroll
        for (int cc = 0; cc < 32; ++cc) {
            const int c = seg + (cc << 2);
            const float v = Crow[c];
            if (v > best) { best = v; bc = c; }
        }
        s_pv[rloc][seg] = best; s_pc[rloc][seg] = bc;
        __syncthreads();
        if (seg == 0) {
            float bv = best; int bcc = bc;
            #pragma unroll
            for (int s2 = 1; s2 < 4; ++s2) {
                const float v = s_pv[rloc][s2]; const int c2 = s_pc[rloc][s2];
                if (c2 >= 0 && (v > bv || (v == bv && (bcc < 0 || c2 < bcc)))) { bv = v; bcc = c2; }
            }
            const size_t base = ((size_t)(b * TT + irow) * NJC + jc) * KMAX + k;
            pval[base] = bv;
            pidx[base] = (bcc >= 0) ? (j0 + bcc) : -1;
            if (bcc >= 0) Crow[bcc] = -INFINITY;
        }
        __syncthreads();
    }
}

// ---- Kernel T: merge window top-Ks, gather, epilogue; optional plane emit / finalize ----
__global__ __launch_bounds__(NTHREADS) void merge_agg_kernel(
    const float* __restrict__ h_in,
    float* __restrict__ h_out,
    const float* __restrict__ pval,
    const int*   __restrict__ pidx,
    const float* __restrict__ gain,
    const float* __restrict__ bias,
    const float* __restrict__ log_mix_r,
    const float* __restrict__ log_momentum,
    int K,
    const float* __restrict__ xres,       // non-null => fused (h-x)*scale
    const float* __restrict__ log_scale,
    _Float16* __restrict__ hiO,           // non-null => emit fp16 planes of h_out
    _Float16* __restrict__ loO)
{
    __shared__ float s_wv[4];
    __shared__ int   s_wj[4];
    __shared__ int   s_sel[KMAX];

    const int row = blockIdx.x, b = row / TT, i = row % TT;
    const int tid = threadIdx.x, lane = tid & 63, wave = tid >> 6;
    const float* hb = h_in + (size_t)b * TT * DD;

    const int jcn = i / CT + 1;
    const int ncand = jcn * K;          // <= 256
    float mv = -INFINITY; int mj = -1;
    if (tid < ncand) {
        const int w = tid / K, k = tid - w * K;
        const size_t base = ((size_t)(b * TT + i) * NJC + w) * KMAX + k;
        const int j = pidx[base];
        if (j >= 0) { mj = j; mv = pval[base]; }
    }

    const int count = (i + 1 < K) ? (i + 1) : K;
    for (int k = 0; k < count; ++k) {
        float v = mv; int j = mj;
        #pragma unroll
        for (int off = 32; off >= 1; off >>= 1) {
            const float ov = __shfl_down(v, off, 64);
            const int   oj = __shfl_down(j, off, 64);
            if (oj >= 0 && (ov > v || (ov == v && (j < 0 || oj < j)))) { v = ov; j = oj; }
        }
        if (lane == 0) { s_wv[wave] = v; s_wj[wave] = j; }
        __syncthreads();
        if (tid == 0) {
            float bv = s_wv[0]; int bj = s_wj[0];
            #pragma unroll
            for (int w = 1; w < 4; ++w) {
                const float wv = s_wv[w]; const int wj = s_wj[w];
                if (wj >= 0 && (wv > bv || (wv == bv && (bj < 0 || wj < bj)))) { bv = wv; bj = wj; }
            }
            s_sel[k] = bj;
        }
        __syncthreads();
        if (mj >= 0 && mj == s_sel[k]) { mv = -INFINITY; mj = -1; }
    }

    const float mix      = 1.0f / (1.0f + expf(-log_mix_r[0]));
    const float momentum = 1.0f / (1.0f + expf(-log_momentum[0]));
    const float inv_cnt  = 1.0f / (float)count;

    float4 msg = make_float4(0.f, 0.f, 0.f, 0.f);
    for (int k = 0; k < count; ++k) {
        const float4 v = ((const float4*)(hb + (size_t)s_sel[k] * DD))[tid];
        msg.x += v.x; msg.y += v.y; msg.z += v.z; msg.w += v.w;
    }

    const float4 hi = ((const float4*)(hb + (size_t)i * DD))[tid];
    const float4 g4 = ((const float4*)gain)[tid];
    const float4 c4 = ((const float4*)bias)[tid];

    float4 o;
    {
        float m, t;
        m = msg.x * inv_cnt; t = (mix * hi.x + (1.f - mix) * m) * g4.x + c4.x;
        o.x = momentum * hi.x + (1.f - momentum) * gelu_exact(t);
        m = msg.y * inv_cnt; t = (mix * hi.y + (1.f - mix) * m) * g4.y + c4.y;
        o.y = momentum * hi.y + (1.f - momentum) * gelu_exact(t);
        m = msg.z * inv_cnt; t = (mix * hi.z + (1.f - mix) * m) * g4.z + c4.z;
        o.z = momentum * hi.z + (1.f - momentum) * gelu_exact(t);
        m = msg.w * inv_cnt; t = (mix * hi.w + (1.f - mix) * m) * g4.w + c4.w;
        o.w = momentum * hi.w + (1.f - momentum) * gelu_exact(t);
    }

    if (hiO != nullptr) {   // planes of h_next (pre-finalize value)
        const float os[4] = {o.x, o.y, o.z, o.w};
        half4v hv, lv;
        #pragma unroll
        for (int u = 0; u < 4; ++u) {
            const _Float16 hh = (_Float16)os[u];
            hv[u] = hh;
            lv[u] = (_Float16)(os[u] - (float)hh);
        }
        const size_t vidx = (size_t)row * (DD / 4) + tid;
        ((half4v*)hiO)[vidx] = hv;
        ((half4v*)loO)[vidx] = lv;
    }

    if (xres != nullptr) {
        const float scale = log1pf(expf(log_scale[0])) + 0.01f;
        const float4 xv = ((const float4*)(xres + (size_t)row * DD))[tid];
        o.x = (o.x - xv.x) * scale;
        o.y = (o.y - xv.y) * scale;
        o.z = (o.z - xv.z) * scale;
        o.w = (o.w - xv.w) * scale;
    }
    ((float4*)(h_out + (size_t)row * DD))[tid] = o;
}

extern "C" void kernel_launch(void* const* d_in, const int* in_sizes, int n_in,
                              void* d_out, int out_size, void* d_ws, size_t ws_size,
                              hipStream_t stream) {
    const float* x            = (const float*)d_in[0];
    const float* gain         = (const float*)d_in[1];
    const float* bias         = (const float*)d_in[2];
    const float* log_mix      = (const float*)d_in[3];
    const float* log_momentum = (const float*)d_in[4];
    const float* log_scale    = (const float*)d_in[5];
    float* out = (float*)d_out;

    // ws: h (16.78 MB) | pval (2.1) | pidx (2.1) | hiP (8.39) | loP (8.39, contiguous after hiP)
    char* wsb = (char*)d_ws;
    float*     h_ws = (float*)wsb;
    float*     pval = (float*)(wsb + (size_t)BB * TT * DD * 4);
    int*       pidx = (int*)  (wsb + (size_t)BB * TT * DD * 4 + (size_t)BB * TT * NJC * KMAX * 4);
    _Float16*  hiP  = (_Float16*)(wsb + (size_t)BB * TT * DD * 4 + (size_t)BB * TT * NJC * KMAX * 8);
    _Float16*  loP  = hiP + (size_t)PLANE;   // must stay contiguous (score kernel offsets)

    const dim3 sgrid(NTILES, BB);
    const int nsplit = BB * TT * DD / 4 / NTHREADS;

    // round 0: x -> out (merge emits planes of h1)
    split_kernel<<<nsplit, NTHREADS, 0, stream>>>(x, hiP, loP);
    score_topk_kernel<<<sgrid, NTHREADS, 0, stream>>>(hiP, pval, pidx, 4);
    merge_agg_kernel<<<BB * TT, NTHREADS, 0, stream>>>(
        x, out, pval, pidx, gain + 0 * DD, bias + 0 * DD, log_mix + 0, log_momentum, 4,
        nullptr, nullptr, hiP, loP);
    // round 1: out -> h_ws (merge emits planes of h2)
    score_topk_kernel<<<sgrid, NTHREADS, 0, stream>>>(hiP, pval, pidx, 8);
    merge_agg_kernel<<<BB * TT, NTHREADS, 0, stream>>>(
        out, h_ws, pval, pidx, gain + 1 * DD, bias + 1 * DD, log_mix + 1, log_momentum, 8,
        nullptr, nullptr, hiP, loP);
    // round 2 (fused finalize): h_ws -> out
    score_topk_kernel<<<sgrid, NTHREADS, 0, stream>>>(hiP, pval, pidx, 16);
    merge_agg_kernel<<<BB * TT, NTHREADS, 0, stream>>>(
        h_ws, out, pval, pidx, gain + 2 * DD, bias + 2 * DD, log_mix + 2, log_momentum, 16,
        x, log_scale, nullptr, nullptr);
}